// Round 1
// baseline (6555.699 us; speedup 1.0000x reference)
//
#include <hip/hip_runtime.h>

typedef short bfx8 __attribute__((ext_vector_type(8)));   // 8 bf16 (bit pattern)
typedef float f32x4 __attribute__((ext_vector_type(4)));
typedef unsigned short ushort_t;
typedef unsigned int uint_t;

__device__ inline ushort_t f2bf(float x) {
    union { float f; uint_t u; } v; v.f = x;
    uint_t r = v.u + 0x7fffu + ((v.u >> 16) & 1u);   // RNE
    return (ushort_t)(r >> 16);
}
__device__ inline float bf2f(ushort_t b) {
    union { uint_t u; float f; } v; v.u = ((uint_t)b) << 16;
    return v.f;
}

// ---------------- fp32 -> bf16 conversion (vectorized) ----------------
__global__ void f2bf_kernel(const float* __restrict__ in, ushort_t* __restrict__ out, int n4) {
    int i = blockIdx.x * 256 + threadIdx.x;
    if (i < n4) {
        float4 v = ((const float4*)in)[i];
        ushort4 o;
        o.x = f2bf(v.x); o.y = f2bf(v.y); o.z = f2bf(v.z); o.w = f2bf(v.w);
        ((ushort4*)out)[i] = o;
    }
}

__global__ void zero_kernel(uint_t* __restrict__ p, int n) {
    int i = blockIdx.x * 256 + threadIdx.x;
    if (i < n) p[i] = 0u;
}

// ---------------- generic bf16 GEMM: C[M,N] = A[M,K] @ Bw[N,K]^T + bias ----------------
// 128x128 tile, BK=64, 4 waves (2x2), each wave 64x64 via 4x4 frags of 16x16x32 MFMA.
#define BM 128
#define BN 128
#define BKK 64
#define LDT 88   // padded LDS row stride in bf16 elems (176B: 16B-aligned, 2-way bank max)

template<int RELU, int OUT_BF16, int HAS_B2>
__global__ __launch_bounds__(256)
void gemm_bt(const ushort_t* __restrict__ A, const ushort_t* __restrict__ Bw,
             const float* __restrict__ bias1, const float* __restrict__ bias2,
             float* __restrict__ Cf, ushort_t* __restrict__ Cb,
             int M, int N, int K)
{
    __shared__ ushort_t As[BM][LDT];
    __shared__ ushort_t Bs[BN][LDT];
    const int tid = threadIdx.x;
    const int l = tid & 63;
    const int wv = tid >> 6;
    const int wm = wv >> 1, wn = wv & 1;
    const int nbm = M / BM;
    const int im = blockIdx.x % nbm;
    const int in = blockIdx.x / nbm;
    const int m0 = im * BM, n0 = in * BN;

    f32x4 acc[4][4];
#pragma unroll
    for (int i = 0; i < 4; i++)
#pragma unroll
        for (int j = 0; j < 4; j++) acc[i][j] = {0.f, 0.f, 0.f, 0.f};

    for (int k0 = 0; k0 < K; k0 += BKK) {
#pragma unroll
        for (int i = 0; i < 4; ++i) {                 // stage A tile: 128x64 bf16
            int c = i * 256 + tid;                    // 1024 chunks of 8 bf16
            int row = c >> 3, cb = c & 7;
            *(bfx8*)&As[row][cb * 8] = *(const bfx8*)&A[(size_t)(m0 + row) * K + k0 + cb * 8];
        }
#pragma unroll
        for (int i = 0; i < 4; ++i) {                 // stage B tile
            int c = i * 256 + tid;
            int row = c >> 3, cb = c & 7;
            *(bfx8*)&Bs[row][cb * 8] = *(const bfx8*)&Bw[(size_t)(n0 + row) * K + k0 + cb * 8];
        }
        __syncthreads();
#pragma unroll
        for (int kk = 0; kk < 2; ++kk) {
            bfx8 av[4], bv[4];
#pragma unroll
            for (int i = 0; i < 4; i++)
                av[i] = *(const bfx8*)&As[wm * 64 + i * 16 + (l & 15)][kk * 32 + (l >> 4) * 8];
#pragma unroll
            for (int i = 0; i < 4; i++)
                bv[i] = *(const bfx8*)&Bs[wn * 64 + i * 16 + (l & 15)][kk * 32 + (l >> 4) * 8];
#pragma unroll
            for (int i = 0; i < 4; i++)
#pragma unroll
                for (int j = 0; j < 4; j++)
                    acc[i][j] = __builtin_amdgcn_mfma_f32_16x16x32_bf16(av[i], bv[j], acc[i][j], 0, 0, 0);
        }
        __syncthreads();
    }

    // epilogue: D row = (l>>4)*4+reg, col = l&15  [verified m89 layout]
#pragma unroll
    for (int j = 0; j < 4; j++) {
        int n = n0 + wn * 64 + j * 16 + (l & 15);
        float bi = bias1[n] + (HAS_B2 ? bias2[n] : 0.0f);
#pragma unroll
        for (int i = 0; i < 4; i++) {
            int mbase = m0 + wm * 64 + i * 16 + (l >> 4) * 4;
#pragma unroll
            for (int r = 0; r < 4; r++) {
                float v = acc[i][j][r] + bi;
                if (RELU) v = fmaxf(v, 0.0f);
                size_t idx = (size_t)(mbase + r) * N + n;
                if (OUT_BF16) Cb[idx] = f2bf(v);
                else          Cf[idx] = v;
            }
        }
    }
}

// ---------------- persistent recurrence kernel ----------------
// 64 WGs = 4 batch-groups x 16 j-slices. Each WG: 4 waves, W_hh slice (64 rows) in VGPRs
// (wave v owns rows j0+16v..+16; lane holds row j0+16v+(l&15), 128 VGPRs of W).
// Per step: stage group h (16x1024 bf16) to LDS, 32 MFMAs/wave, epilogue z+relu, group barrier.
#define T_STEPS 512

__global__ __launch_bounds__(256, 1)
void recurrence_kernel(const ushort_t* __restrict__ Z,     // [T*64,1024] bf16
                       const float* __restrict__ W_hh,     // [1024,1024] fp32
                       float* __restrict__ Hout,           // [T,64,1024] fp32 (d_out)
                       ushort_t* __restrict__ hb,          // [T*64,1024] bf16
                       uint_t* __restrict__ cnt)           // [T][4]
{
    __shared__ ushort_t Hs[16][1048];                      // 16 rows x (1024+24) pad
    const int tid = threadIdx.x;
    const int l = tid & 63;
    const int v = tid >> 6;                // wave 0..3
    const int g = blockIdx.x >> 4;         // batch group 0..3
    const int w = blockIdx.x & 15;         // j-slice 0..15
    const int bg0 = g * 16;
    const int jcol = w * 64 + v * 16 + (l & 15);

    // one-time W_hh preload into registers (fp32 -> bf16)
    bfx8 wreg[32];
#pragma unroll
    for (int k0 = 0; k0 < 32; k0++) {
        const float* p = &W_hh[(size_t)jcol * 1024 + k0 * 32 + (l >> 4) * 8];
        float4 f0 = *(const float4*)p;
        float4 f1 = *(const float4*)(p + 4);
        bfx8 t;
        t[0] = (short)f2bf(f0.x); t[1] = (short)f2bf(f0.y);
        t[2] = (short)f2bf(f0.z); t[3] = (short)f2bf(f0.w);
        t[4] = (short)f2bf(f1.x); t[5] = (short)f2bf(f1.y);
        t[6] = (short)f2bf(f1.z); t[7] = (short)f2bf(f1.w);
        wreg[k0] = t;
    }

    for (int t = 0; t < T_STEPS; t++) {
        f32x4 acc = {0.f, 0.f, 0.f, 0.f};
        if (t > 0) {
            // stage hb[t-1][bg0..bg0+16][:] -> LDS (coalesced, 32KB)
#pragma unroll
            for (int i = 0; i < 8; i++) {
                int c = i * 256 + tid;                 // 2048 chunks of 8 bf16
                int row = c >> 7, cb = c & 127;
                *(bfx8*)&Hs[row][cb * 8] =
                    *(const bfx8*)&hb[((size_t)(t - 1) * 64 + bg0 + row) * 1024 + cb * 8];
            }
            __syncthreads();
#pragma unroll
            for (int k0 = 0; k0 < 32; k0++) {
                bfx8 a = *(const bfx8*)&Hs[l & 15][k0 * 32 + (l >> 4) * 8];
                acc = __builtin_amdgcn_mfma_f32_16x16x32_bf16(a, wreg[k0], acc, 0, 0, 0);
            }
        }
        // epilogue: lane holds h_new[b=(bg0+(l>>4)*4+r)][jcol]
#pragma unroll
        for (int r = 0; r < 4; r++) {
            int b = bg0 + (l >> 4) * 4 + r;
            size_t zi = ((size_t)t * 64 + b) * 1024 + jcol;
            float hv = bf2f(Z[zi]) + acc[r];
            hv = fmaxf(hv, 0.f);
            Hout[zi] = hv;
            hb[zi] = f2bf(hv);
        }
        // group barrier: release writes, arrive, spin until all 16 slices done
        __syncthreads();
        __threadfence();
        if (tid == 0) {
            atomicAdd(&cnt[t * 4 + g], 1u);
            while (__hip_atomic_load(&cnt[t * 4 + g], __ATOMIC_RELAXED,
                                     __HIP_MEMORY_SCOPE_AGENT) < 16u) {
                __builtin_amdgcn_s_sleep(2);
            }
        }
        __syncthreads();
        __threadfence();   // acquire: invalidate caches before reading others' h slices
    }
}

extern "C" void kernel_launch(void* const* d_in, const int* in_sizes, int n_in,
                              void* d_out, int out_size, void* d_ws, size_t ws_size,
                              hipStream_t stream) {
    const float* in_sig = (const float*)d_in[0];   // [512,64,256]
    const float* W_in  = (const float*)d_in[2];    // [1024,256]
    const float* b_in  = (const float*)d_in[3];
    const float* W_ih  = (const float*)d_in[4];    // [1024,1024]
    const float* b_ih  = (const float*)d_in[5];
    const float* W_hh  = (const float*)d_in[6];    // [1024,1024]
    const float* b_hh  = (const float*)d_in[7];
    const float* W_out = (const float*)d_in[8];    // [256,1024]
    const float* b_out = (const float*)d_in[9];

    char* ws = (char*)d_ws;
    const size_t MB = 1ull << 20;
    // layout (hb aliases the region dead after phase 2):
    ushort_t* inb   = (ushort_t*)(ws + 0);          // 16 MB  [0,16)
    ushort_t* Winb  = (ushort_t*)(ws + 17 * MB);    // 0.5 MB
    ushort_t* Wihb  = (ushort_t*)(ws + 18 * MB);    // 2 MB
    ushort_t* Xb    = (ushort_t*)(ws + 21 * MB);    // 64 MB  [21,85)
    ushort_t* hb    = (ushort_t*)(ws + 0);          // 64 MB  alias [0,64) — inb/Winb/Wihb/X dead by then
    ushort_t* Woutb = (ushort_t*)(ws + 85 * MB);    // 0.5 MB
    ushort_t* Zb    = (ushort_t*)(ws + 86 * MB);    // 64 MB  [86,150)
    uint_t*   cnt   = (uint_t*)(ws + 150 * MB);     // 8 KB

    float* hiddens = (float*)d_out;                      // [512,64,1024]
    float* outputs = (float*)d_out + 33554432;           // [512,64,256]

    // fp32 -> bf16 conversions
    f2bf_kernel<<<8192, 256, 0, stream>>>(in_sig, inb, 2097152);
    f2bf_kernel<<<256, 256, 0, stream>>>(W_in, Winb, 65536);
    f2bf_kernel<<<1024, 256, 0, stream>>>(W_ih, Wihb, 262144);
    f2bf_kernel<<<256, 256, 0, stream>>>(W_out, Woutb, 65536);

    // X = relu(In @ W_in^T + b_in)  [32768,1024] bf16
    gemm_bt<1, 1, 0><<<2048, 256, 0, stream>>>(inb, Winb, b_in, nullptr,
                                               nullptr, Xb, 32768, 1024, 256);
    // Z = X @ W_ih^T + b_ih + b_hh  [32768,1024] bf16
    gemm_bt<0, 1, 1><<<2048, 256, 0, stream>>>(Xb, Wihb, b_ih, b_hh,
                                               nullptr, Zb, 32768, 1024, 1024);

    zero_kernel<<<8, 256, 0, stream>>>(cnt, 2048);

    // sequential recurrence: h_t = relu(Z_t + h_{t-1} @ W_hh^T), writes hiddens + hb(bf16)
    recurrence_kernel<<<64, 256, 0, stream>>>(Zb, W_hh, hiddens, hb, cnt);

    // O = H @ W_out^T + b_out  [32768,256] fp32
    gemm_bt<0, 0, 0><<<512, 256, 0, stream>>>(hb, Woutb, b_out, nullptr,
                                              outputs, nullptr, 32768, 256, 1024);
}

// Round 2
// 1712.285 us; speedup vs baseline: 3.8286x; 3.8286x over previous
//
#include <hip/hip_runtime.h>

typedef short bfx8 __attribute__((ext_vector_type(8)));   // 8 bf16 (bit pattern)
typedef float f32x4 __attribute__((ext_vector_type(4)));
typedef unsigned short ushort_t;
typedef unsigned int uint_t;
typedef unsigned long long ull_t;

__device__ inline ushort_t f2bf(float x) {
    union { float f; uint_t u; } v; v.f = x;
    uint_t r = v.u + 0x7fffu + ((v.u >> 16) & 1u);   // RNE
    return (ushort_t)(r >> 16);
}
__device__ inline float bf2f(ushort_t b) {
    union { uint_t u; float f; } v; v.u = ((uint_t)b) << 16;
    return v.f;
}

// ---------------- fp32 -> bf16 conversion (vectorized) ----------------
__global__ void f2bf_kernel(const float* __restrict__ in, ushort_t* __restrict__ out, int n4) {
    int i = blockIdx.x * 256 + threadIdx.x;
    if (i < n4) {
        float4 v = ((const float4*)in)[i];
        ushort4 o;
        o.x = f2bf(v.x); o.y = f2bf(v.y); o.z = f2bf(v.z); o.w = f2bf(v.w);
        ((ushort4*)out)[i] = o;
    }
}

__global__ void zero_kernel(uint_t* __restrict__ p, int n) {
    int i = blockIdx.x * 256 + threadIdx.x;
    if (i < n) p[i] = 0u;
}

// ---------------- generic bf16 GEMM: C[M,N] = A[M,K] @ Bw[N,K]^T + bias ----------------
#define BM 128
#define BN 128
#define BKK 64
#define LDT 88   // padded LDS row stride in bf16 elems

template<int RELU, int OUT_BF16, int HAS_B2>
__global__ __launch_bounds__(256)
void gemm_bt(const ushort_t* __restrict__ A, const ushort_t* __restrict__ Bw,
             const float* __restrict__ bias1, const float* __restrict__ bias2,
             float* __restrict__ Cf, ushort_t* __restrict__ Cb,
             int M, int N, int K)
{
    __shared__ ushort_t As[BM][LDT];
    __shared__ ushort_t Bs[BN][LDT];
    const int tid = threadIdx.x;
    const int l = tid & 63;
    const int wv = tid >> 6;
    const int wm = wv >> 1, wn = wv & 1;
    const int nbm = M / BM;
    const int im = blockIdx.x % nbm;
    const int in = blockIdx.x / nbm;
    const int m0 = im * BM, n0 = in * BN;

    f32x4 acc[4][4];
#pragma unroll
    for (int i = 0; i < 4; i++)
#pragma unroll
        for (int j = 0; j < 4; j++) acc[i][j] = {0.f, 0.f, 0.f, 0.f};

    for (int k0 = 0; k0 < K; k0 += BKK) {
#pragma unroll
        for (int i = 0; i < 4; ++i) {                 // stage A tile: 128x64 bf16
            int c = i * 256 + tid;
            int row = c >> 3, cb = c & 7;
            *(bfx8*)&As[row][cb * 8] = *(const bfx8*)&A[(size_t)(m0 + row) * K + k0 + cb * 8];
        }
#pragma unroll
        for (int i = 0; i < 4; ++i) {                 // stage B tile
            int c = i * 256 + tid;
            int row = c >> 3, cb = c & 7;
            *(bfx8*)&Bs[row][cb * 8] = *(const bfx8*)&Bw[(size_t)(n0 + row) * K + k0 + cb * 8];
        }
        __syncthreads();
#pragma unroll
        for (int kk = 0; kk < 2; ++kk) {
            bfx8 av[4], bv[4];
#pragma unroll
            for (int i = 0; i < 4; i++)
                av[i] = *(const bfx8*)&As[wm * 64 + i * 16 + (l & 15)][kk * 32 + (l >> 4) * 8];
#pragma unroll
            for (int i = 0; i < 4; i++)
                bv[i] = *(const bfx8*)&Bs[wn * 64 + i * 16 + (l & 15)][kk * 32 + (l >> 4) * 8];
#pragma unroll
            for (int i = 0; i < 4; i++)
#pragma unroll
                for (int j = 0; j < 4; j++)
                    acc[i][j] = __builtin_amdgcn_mfma_f32_16x16x32_bf16(av[i], bv[j], acc[i][j], 0, 0, 0);
        }
        __syncthreads();
    }

#pragma unroll
    for (int j = 0; j < 4; j++) {
        int n = n0 + wn * 64 + j * 16 + (l & 15);
        float bi = bias1[n] + (HAS_B2 ? bias2[n] : 0.0f);
#pragma unroll
        for (int i = 0; i < 4; i++) {
            int mbase = m0 + wm * 64 + i * 16 + (l >> 4) * 4;
#pragma unroll
            for (int r = 0; r < 4; r++) {
                float v = acc[i][j][r] + bi;
                if (RELU) v = fmaxf(v, 0.0f);
                size_t idx = (size_t)(mbase + r) * N + n;
                if (OUT_BF16) Cb[idx] = f2bf(v);
                else          Cf[idx] = v;
            }
        }
    }
}

// ---------------- persistent recurrence kernel (flag-pipelined, no L2 fences) ----------------
// 64 WGs = 4 batch-groups x 16 j-slices. Group g owns batch rows g*16..+16; WG w owns cols w*64..+64.
// Comm data goes through agent-scope (sc1) atomics -> coherent at L3, no buffer_wbl2/buffer_inv ever.
#define T_STEPS 512

__global__ __launch_bounds__(256, 1)
void recurrence_kernel(const ushort_t* __restrict__ Z,     // [T*64,1024] bf16
                       const float* __restrict__ W_hh,     // [1024,1024] fp32
                       float* __restrict__ Hout,           // [T,64,1024] fp32 (d_out)
                       ushort_t* __restrict__ hb,          // [T*64,1024] bf16
                       uint_t* __restrict__ flags)         // [4][16] monotone step counters
{
    __shared__ ushort_t Hs[16][1048];   // group h staging (pad 24 -> bank-spread rows)
    __shared__ ushort_t Es[16][72];     // epilogue transpose buffer (own 16x64 slice)
    const int tid = threadIdx.x;
    const int l = tid & 63;
    const int v = tid >> 6;                // wave 0..3
    const int g = blockIdx.x >> 4;         // batch group 0..3
    const int w = blockIdx.x & 15;         // j-slice 0..15
    const int b0 = g * 16;
    const int jcol = w * 64 + v * 16 + (l & 15);
    uint_t* myflags = flags + g * 16;

    // one-time W_hh slice preload into registers (fp32 -> bf16), 128 VGPRs
    bfx8 wreg[32];
#pragma unroll
    for (int k0 = 0; k0 < 32; k0++) {
        const float* p = &W_hh[(size_t)jcol * 1024 + k0 * 32 + (l >> 4) * 8];
        float4 f0 = *(const float4*)p;
        float4 f1 = *(const float4*)(p + 4);
        bfx8 t;
        t[0] = (short)f2bf(f0.x); t[1] = (short)f2bf(f0.y);
        t[2] = (short)f2bf(f0.z); t[3] = (short)f2bf(f0.w);
        t[4] = (short)f2bf(f1.x); t[5] = (short)f2bf(f1.y);
        t[6] = (short)f2bf(f1.z); t[7] = (short)f2bf(f1.w);
        wreg[k0] = t;
    }

    for (int t = 0; t < T_STEPS; t++) {
        f32x4 acc = {0.f, 0.f, 0.f, 0.f};
        if (t > 0) {
            // h_{t-1} (full group row block) is in Hs
#pragma unroll
            for (int k0 = 0; k0 < 32; k0++) {
                bfx8 a = *(const bfx8*)&Hs[l & 15][k0 * 32 + (l >> 4) * 8];
                acc = __builtin_amdgcn_mfma_f32_16x16x32_bf16(a, wreg[k0], acc, 0, 0, 0);
            }
        }
        // epilogue: lane holds h_new[b0+(l>>4)*4+r][jcol]
#pragma unroll
        for (int r = 0; r < 4; r++) {
            int br = (l >> 4) * 4 + r;
            size_t zi = ((size_t)t * 64 + b0 + br) * 1024 + jcol;
            float hv = bf2f(Z[zi]) + acc[r];
            hv = fmaxf(hv, 0.f);
            __builtin_nontemporal_store(hv, &Hout[zi]);       // fp32 output, bypass L2
            Es[br][v * 16 + (l & 15)] = f2bf(hv);             // local transpose buffer
        }
        __syncthreads();   // Es complete

        // pack own 16x64 slice -> hb via coalesced 8B agent-scope stores (256 chunks)
        {
            int row = tid >> 4, lc = (tid & 15) * 4;
            ull_t val = *(const ull_t*)&Es[row][lc];
            ull_t* dst = (ull_t*)&hb[((size_t)t * 64 + b0 + row) * 1024 + w * 64 + lc];
            __hip_atomic_store(dst, val, __ATOMIC_RELAXED, __HIP_MEMORY_SCOPE_AGENT);
        }

        if (t < T_STEPS - 1) {
            __syncthreads();   // drains vmcnt -> slice globally visible (sc1 write-through)
            if (tid == 0)
                __hip_atomic_store(&myflags[w], (uint_t)(t + 1),
                                   __ATOMIC_RELAXED, __HIP_MEMORY_SCOPE_AGENT);
            if (tid < 16) {    // each of 16 threads spins on one slice flag
                while (__hip_atomic_load(&myflags[tid], __ATOMIC_RELAXED,
                                         __HIP_MEMORY_SCOPE_AGENT) < (uint_t)(t + 1))
                    __builtin_amdgcn_s_sleep(1);
            }
            __syncthreads();   // all 16 slices published

            // stage full group h_t (16 rows x 1024 cols = 32KB) -> Hs.
            // 4096 ulongs, 16 per thread; load all into regs first (pipelined), then ds_write.
            const ull_t* src = (const ull_t*)&hb[((size_t)t * 64 + b0) * 1024];
            ull_t sv[16];
#pragma unroll
            for (int i = 0; i < 16; i++)
                sv[i] = __hip_atomic_load(src + (size_t)i * 256 + tid,
                                          __ATOMIC_RELAXED, __HIP_MEMORY_SCOPE_AGENT);
#pragma unroll
            for (int i = 0; i < 16; i++)
                *(ull_t*)&Hs[i][tid * 4] = sv[i];
            __syncthreads();   // Hs ready for next step's MFMA
        }
    }
}

extern "C" void kernel_launch(void* const* d_in, const int* in_sizes, int n_in,
                              void* d_out, int out_size, void* d_ws, size_t ws_size,
                              hipStream_t stream) {
    const float* in_sig = (const float*)d_in[0];   // [512,64,256]
    const float* W_in  = (const float*)d_in[2];    // [1024,256]
    const float* b_in  = (const float*)d_in[3];
    const float* W_ih  = (const float*)d_in[4];    // [1024,1024]
    const float* b_ih  = (const float*)d_in[5];
    const float* W_hh  = (const float*)d_in[6];    // [1024,1024]
    const float* b_hh  = (const float*)d_in[7];
    const float* W_out = (const float*)d_in[8];    // [256,1024]
    const float* b_out = (const float*)d_in[9];

    char* ws = (char*)d_ws;
    const size_t MB = 1ull << 20;
    ushort_t* inb   = (ushort_t*)(ws + 0);          // 16 MB  [0,16)
    ushort_t* Winb  = (ushort_t*)(ws + 17 * MB);    // 0.5 MB
    ushort_t* Wihb  = (ushort_t*)(ws + 18 * MB);    // 2 MB
    ushort_t* Xb    = (ushort_t*)(ws + 21 * MB);    // 64 MB  [21,85)
    ushort_t* hb    = (ushort_t*)(ws + 0);          // 64 MB  alias [0,64) — dead by then
    ushort_t* Woutb = (ushort_t*)(ws + 85 * MB);    // 0.5 MB
    ushort_t* Zb    = (ushort_t*)(ws + 86 * MB);    // 64 MB  [86,150)
    uint_t*   flags = (uint_t*)(ws + 150 * MB);     // 256 B

    float* hiddens = (float*)d_out;                      // [512,64,1024]
    float* outputs = (float*)d_out + 33554432;           // [512,64,256]

    f2bf_kernel<<<8192, 256, 0, stream>>>(in_sig, inb, 2097152);
    f2bf_kernel<<<256, 256, 0, stream>>>(W_in, Winb, 65536);
    f2bf_kernel<<<1024, 256, 0, stream>>>(W_ih, Wihb, 262144);
    f2bf_kernel<<<256, 256, 0, stream>>>(W_out, Woutb, 65536);

    // X = relu(In @ W_in^T + b_in)  [32768,1024] bf16
    gemm_bt<1, 1, 0><<<2048, 256, 0, stream>>>(inb, Winb, b_in, nullptr,
                                               nullptr, Xb, 32768, 1024, 256);
    // Z = X @ W_ih^T + b_ih + b_hh  [32768,1024] bf16
    gemm_bt<0, 1, 1><<<2048, 256, 0, stream>>>(Xb, Wihb, b_ih, b_hh,
                                               nullptr, Zb, 32768, 1024, 1024);

    zero_kernel<<<1, 256, 0, stream>>>(flags, 64);

    // sequential recurrence: h_t = relu(Z_t + h_{t-1} @ W_hh^T)
    recurrence_kernel<<<64, 256, 0, stream>>>(Zb, W_hh, hiddens, hb, flags);

    // O = H @ W_out^T + b_out  [32768,256] fp32
    gemm_bt<0, 0, 0><<<512, 256, 0, stream>>>(hb, Woutb, b_out, nullptr,
                                              outputs, nullptr, 32768, 256, 1024);
}

// Round 3
// 1561.965 us; speedup vs baseline: 4.1971x; 1.0962x over previous
//
#include <hip/hip_runtime.h>

typedef short bfx8 __attribute__((ext_vector_type(8)));   // 8 bf16 (bit pattern)
typedef float f32x4 __attribute__((ext_vector_type(4)));
typedef unsigned short ushort_t;
typedef unsigned int uint_t;
typedef unsigned long long ull_t;

__device__ inline ushort_t f2bf(float x) {
    union { float f; uint_t u; } v; v.f = x;
    uint_t r = v.u + 0x7fffu + ((v.u >> 16) & 1u);   // RNE
    return (ushort_t)(r >> 16);
}
__device__ inline float bf2f(ushort_t b) {
    union { uint_t u; float f; } v; v.u = ((uint_t)b) << 16;
    return v.f;
}

// ---------------- fp32 -> bf16 conversion (vectorized) ----------------
__global__ void f2bf_kernel(const float* __restrict__ in, ushort_t* __restrict__ out, int n4) {
    int i = blockIdx.x * 256 + threadIdx.x;
    if (i < n4) {
        float4 v = ((const float4*)in)[i];
        ushort4 o;
        o.x = f2bf(v.x); o.y = f2bf(v.y); o.z = f2bf(v.z); o.w = f2bf(v.w);
        ((ushort4*)out)[i] = o;
    }
}

__global__ void zero_kernel(uint_t* __restrict__ p, int n) {
    int i = blockIdx.x * 256 + threadIdx.x;
    if (i < n) p[i] = 0u;
}

// ---------------- generic bf16 GEMM: C[M,N] = A[M,K] @ Bw[N,K]^T + bias ----------------
#define BM 128
#define BN 128
#define BKK 64
#define LDT 88   // padded LDS row stride in bf16 elems

template<int RELU, int OUT_BF16, int HAS_B2>
__global__ __launch_bounds__(256)
void gemm_bt(const ushort_t* __restrict__ A, const ushort_t* __restrict__ Bw,
             const float* __restrict__ bias1, const float* __restrict__ bias2,
             float* __restrict__ Cf, ushort_t* __restrict__ Cb,
             int M, int N, int K)
{
    __shared__ ushort_t As[BM][LDT];
    __shared__ ushort_t Bs[BN][LDT];
    const int tid = threadIdx.x;
    const int l = tid & 63;
    const int wv = tid >> 6;
    const int wm = wv >> 1, wn = wv & 1;
    const int nbm = M / BM;
    const int im = blockIdx.x % nbm;
    const int in = blockIdx.x / nbm;
    const int m0 = im * BM, n0 = in * BN;

    f32x4 acc[4][4];
#pragma unroll
    for (int i = 0; i < 4; i++)
#pragma unroll
        for (int j = 0; j < 4; j++) acc[i][j] = {0.f, 0.f, 0.f, 0.f};

    for (int k0 = 0; k0 < K; k0 += BKK) {
#pragma unroll
        for (int i = 0; i < 4; ++i) {                 // stage A tile: 128x64 bf16
            int c = i * 256 + tid;
            int row = c >> 3, cb = c & 7;
            *(bfx8*)&As[row][cb * 8] = *(const bfx8*)&A[(size_t)(m0 + row) * K + k0 + cb * 8];
        }
#pragma unroll
        for (int i = 0; i < 4; ++i) {                 // stage B tile
            int c = i * 256 + tid;
            int row = c >> 3, cb = c & 7;
            *(bfx8*)&Bs[row][cb * 8] = *(const bfx8*)&Bw[(size_t)(n0 + row) * K + k0 + cb * 8];
        }
        __syncthreads();
#pragma unroll
        for (int kk = 0; kk < 2; ++kk) {
            bfx8 av[4], bv[4];
#pragma unroll
            for (int i = 0; i < 4; i++)
                av[i] = *(const bfx8*)&As[wm * 64 + i * 16 + (l & 15)][kk * 32 + (l >> 4) * 8];
#pragma unroll
            for (int i = 0; i < 4; i++)
                bv[i] = *(const bfx8*)&Bs[wn * 64 + i * 16 + (l & 15)][kk * 32 + (l >> 4) * 8];
#pragma unroll
            for (int i = 0; i < 4; i++)
#pragma unroll
                for (int j = 0; j < 4; j++)
                    acc[i][j] = __builtin_amdgcn_mfma_f32_16x16x32_bf16(av[i], bv[j], acc[i][j], 0, 0, 0);
        }
        __syncthreads();
    }

#pragma unroll
    for (int j = 0; j < 4; j++) {
        int n = n0 + wn * 64 + j * 16 + (l & 15);
        float bi = bias1[n] + (HAS_B2 ? bias2[n] : 0.0f);
#pragma unroll
        for (int i = 0; i < 4; i++) {
            int mbase = m0 + wm * 64 + i * 16 + (l >> 4) * 4;
#pragma unroll
            for (int r = 0; r < 4; r++) {
                float v = acc[i][j][r] + bi;
                if (RELU) v = fmaxf(v, 0.0f);
                size_t idx = (size_t)(mbase + r) * N + n;
                if (OUT_BF16) Cb[idx] = f2bf(v);
                else          Cf[idx] = v;
            }
        }
    }
}

// ---------------- persistent recurrence kernel (flag-pipelined, latency-trimmed) ----------------
// 64 WGs = 4 batch-groups x 16 j-slices. Group g owns batch rows g*16..+16; WG w owns cols w*64..+64.
// Comm via agent-scope (sc1) atomics -> coherent at L3, no wbl2/inv fences.
#define T_STEPS 512

__global__ __launch_bounds__(256, 1)
void recurrence_kernel(const ushort_t* __restrict__ Z,     // [T*64,1024] bf16
                       const float* __restrict__ W_hh,     // [1024,1024] fp32
                       float* __restrict__ Hout,           // [T,64,1024] fp32 (d_out)
                       ushort_t* __restrict__ hb,          // [T*64,1024] bf16
                       uint_t* __restrict__ flags)         // [4][16] monotone step counters
{
    __shared__ ushort_t Hs[16][1048];    // group h staging (stride 2096B -> 2-way max on b128)
    __shared__ ushort_t Es[4][16][16];   // per-wave 16x16 transpose buffers
    const int tid = threadIdx.x;
    const int l = tid & 63;
    const int v = tid >> 6;                // wave 0..3
    const int g = blockIdx.x >> 4;         // batch group 0..3
    const int w = blockIdx.x & 15;         // j-slice 0..15
    const int b0 = g * 16;
    const int jcol = w * 64 + v * 16 + (l & 15);
    const int myslice = tid >> 4;          // slice this thread's stage col-chunk lives in
    uint_t* myflags = flags + g * 16;

    // one-time W_hh slice preload into registers (fp32 -> bf16), 128 VGPRs
    bfx8 wreg[32];
#pragma unroll
    for (int k0 = 0; k0 < 32; k0++) {
        const float* p = &W_hh[(size_t)jcol * 1024 + k0 * 32 + (l >> 4) * 8];
        float4 f0 = *(const float4*)p;
        float4 f1 = *(const float4*)(p + 4);
        bfx8 t;
        t[0] = (short)f2bf(f0.x); t[1] = (short)f2bf(f0.y);
        t[2] = (short)f2bf(f0.z); t[3] = (short)f2bf(f0.w);
        t[4] = (short)f2bf(f1.x); t[5] = (short)f2bf(f1.y);
        t[6] = (short)f2bf(f1.z); t[7] = (short)f2bf(f1.w);
        wreg[k0] = t;
    }

    // Z prefetch for t=0
    float zf[4];
#pragma unroll
    for (int r = 0; r < 4; r++) {
        int br = (l >> 4) * 4 + r;
        zf[r] = bf2f(__builtin_nontemporal_load(&Z[(size_t)(b0 + br) * 1024 + jcol]));
    }

    for (int t = 0; t < T_STEPS; t++) {
        // ---- MFMA: acc = h_{t-1} @ Whh_slice^T  (4-way split accumulator) ----
        f32x4 a0 = {0.f,0.f,0.f,0.f}, a1 = {0.f,0.f,0.f,0.f};
        f32x4 a2 = {0.f,0.f,0.f,0.f}, a3 = {0.f,0.f,0.f,0.f};
        if (t > 0) {
#pragma unroll
            for (int k0 = 0; k0 < 32; k0 += 4) {
                bfx8 h0 = *(const bfx8*)&Hs[l & 15][(k0 + 0) * 32 + (l >> 4) * 8];
                bfx8 h1 = *(const bfx8*)&Hs[l & 15][(k0 + 1) * 32 + (l >> 4) * 8];
                bfx8 h2 = *(const bfx8*)&Hs[l & 15][(k0 + 2) * 32 + (l >> 4) * 8];
                bfx8 h3 = *(const bfx8*)&Hs[l & 15][(k0 + 3) * 32 + (l >> 4) * 8];
                a0 = __builtin_amdgcn_mfma_f32_16x16x32_bf16(h0, wreg[k0 + 0], a0, 0, 0, 0);
                a1 = __builtin_amdgcn_mfma_f32_16x16x32_bf16(h1, wreg[k0 + 1], a1, 0, 0, 0);
                a2 = __builtin_amdgcn_mfma_f32_16x16x32_bf16(h2, wreg[k0 + 2], a2, 0, 0, 0);
                a3 = __builtin_amdgcn_mfma_f32_16x16x32_bf16(h3, wreg[k0 + 3], a3, 0, 0, 0);
            }
        }
        f32x4 acc = (a0 + a1) + (a2 + a3);

        // ---- epilogue: h = relu(z + acc); stash to wave-local transpose buffer ----
        float hv[4];
#pragma unroll
        for (int r = 0; r < 4; r++) {
            int br = (l >> 4) * 4 + r;
            float x = fmaxf(zf[r] + acc[r], 0.f);
            hv[r] = x;
            Es[v][br][l & 15] = f2bf(x);
        }
        asm volatile("s_waitcnt lgkmcnt(0)" ::: "memory");
        __builtin_amdgcn_sched_barrier(0);

        // ---- pack own wave's 16x16 slice -> hb, coalesced 8B agent-scope stores ----
        {
            int row = l & 15, c0 = (l >> 4) * 4;
            ull_t val = *(const ull_t*)&Es[v][row][c0];
            ull_t* dst = (ull_t*)&hb[((size_t)t * 64 + b0 + row) * 1024 + w * 64 + v * 16 + c0];
            __hip_atomic_store(dst, val, __ATOMIC_RELAXED, __HIP_MEMORY_SCOPE_AGENT);
        }

        if (t < T_STEPS - 1) {
            __syncthreads();   // full drain: all pack stores globally visible
            if (tid == 0)
                __hip_atomic_store(&myflags[w], (uint_t)(t + 1),
                                   __ATOMIC_RELAXED, __HIP_MEMORY_SCOPE_AGENT);

            // off-critical-path traffic issued into the wait window:
#pragma unroll
            for (int r = 0; r < 4; r++) {        // fp32 Hout (drains during poll)
                int br = (l >> 4) * 4 + r;
                __builtin_nontemporal_store(hv[r], &Hout[((size_t)t * 64 + b0 + br) * 1024 + jcol]);
            }
#pragma unroll
            for (int r = 0; r < 4; r++) {        // Z prefetch for t+1
                int br = (l >> 4) * 4 + r;
                zf[r] = bf2f(__builtin_nontemporal_load(
                    &Z[((size_t)(t + 1) * 64 + b0 + br) * 1024 + jcol]));
            }

            // poll only the flag of the slice this thread stages, then load immediately
            while (__hip_atomic_load(&myflags[myslice], __ATOMIC_RELAXED,
                                     __HIP_MEMORY_SCOPE_AGENT) < (uint_t)(t + 1))
                __builtin_amdgcn_s_sleep(1);

            const ull_t* src = (const ull_t*)&hb[((size_t)t * 64 + b0) * 1024];
            ull_t sv[16];
#pragma unroll
            for (int i = 0; i < 16; i++)
                sv[i] = __hip_atomic_load(src + (size_t)i * 256 + tid,
                                          __ATOMIC_RELAXED, __HIP_MEMORY_SCOPE_AGENT);
#pragma unroll
            for (int i = 0; i < 16; i++)
                *(ull_t*)&Hs[i][tid * 4] = sv[i];

            // LDS-only barrier: Hs ready; vmem (zf/Hout) drains lazily
            asm volatile("s_waitcnt lgkmcnt(0)" ::: "memory");
            __builtin_amdgcn_s_barrier();
            __builtin_amdgcn_sched_barrier(0);
        } else {
#pragma unroll
            for (int r = 0; r < 4; r++) {
                int br = (l >> 4) * 4 + r;
                __builtin_nontemporal_store(hv[r], &Hout[((size_t)t * 64 + b0 + br) * 1024 + jcol]);
            }
        }
    }
}

extern "C" void kernel_launch(void* const* d_in, const int* in_sizes, int n_in,
                              void* d_out, int out_size, void* d_ws, size_t ws_size,
                              hipStream_t stream) {
    const float* in_sig = (const float*)d_in[0];   // [512,64,256]
    const float* W_in  = (const float*)d_in[2];    // [1024,256]
    const float* b_in  = (const float*)d_in[3];
    const float* W_ih  = (const float*)d_in[4];    // [1024,1024]
    const float* b_ih  = (const float*)d_in[5];
    const float* W_hh  = (const float*)d_in[6];    // [1024,1024]
    const float* b_hh  = (const float*)d_in[7];
    const float* W_out = (const float*)d_in[8];    // [256,1024]
    const float* b_out = (const float*)d_in[9];

    char* ws = (char*)d_ws;
    const size_t MB = 1ull << 20;
    ushort_t* inb   = (ushort_t*)(ws + 0);          // 16 MB  [0,16)
    ushort_t* Winb  = (ushort_t*)(ws + 17 * MB);    // 0.5 MB
    ushort_t* Wihb  = (ushort_t*)(ws + 18 * MB);    // 2 MB
    ushort_t* Xb    = (ushort_t*)(ws + 21 * MB);    // 64 MB  [21,85)
    ushort_t* hb    = (ushort_t*)(ws + 0);          // 64 MB  alias [0,64) — dead by then
    ushort_t* Woutb = (ushort_t*)(ws + 85 * MB);    // 0.5 MB
    ushort_t* Zb    = (ushort_t*)(ws + 86 * MB);    // 64 MB  [86,150)
    uint_t*   flags = (uint_t*)(ws + 150 * MB);     // 256 B

    float* hiddens = (float*)d_out;                      // [512,64,1024]
    float* outputs = (float*)d_out + 33554432;           // [512,64,256]

    f2bf_kernel<<<8192, 256, 0, stream>>>(in_sig, inb, 2097152);
    f2bf_kernel<<<256, 256, 0, stream>>>(W_in, Winb, 65536);
    f2bf_kernel<<<1024, 256, 0, stream>>>(W_ih, Wihb, 262144);
    f2bf_kernel<<<256, 256, 0, stream>>>(W_out, Woutb, 65536);

    // X = relu(In @ W_in^T + b_in)  [32768,1024] bf16
    gemm_bt<1, 1, 0><<<2048, 256, 0, stream>>>(inb, Winb, b_in, nullptr,
                                               nullptr, Xb, 32768, 1024, 256);
    // Z = X @ W_ih^T + b_ih + b_hh  [32768,1024] bf16
    gemm_bt<0, 1, 1><<<2048, 256, 0, stream>>>(Xb, Wihb, b_ih, b_hh,
                                               nullptr, Zb, 32768, 1024, 1024);

    zero_kernel<<<1, 256, 0, stream>>>(flags, 64);

    // sequential recurrence: h_t = relu(Z_t + h_{t-1} @ W_hh^T)
    recurrence_kernel<<<64, 256, 0, stream>>>(Zb, W_hh, hiddens, hb, flags);

    // O = H @ W_out^T + b_out  [32768,256] fp32
    gemm_bt<0, 0, 0><<<512, 256, 0, stream>>>(hb, Woutb, b_out, nullptr,
                                              outputs, nullptr, 32768, 256, 1024);
}